// Round 1
// baseline (401.057 us; speedup 1.0000x reference)
//
#include <hip/hip_runtime.h>
#include <hip/hip_bf16.h>

#define NSEQ 2048
#define HID 128
#define HEADS 8
#define HD 16
#define SCALE 0.25f
#define TQ 8
#define TK 64
#define QROW 160            // padded q row stride (floats): 8 chunks of 16 @ stride 20
#define SROW (HEADS*TQ)     // 64 floats per m-row of S: [m][h][r]

typedef unsigned short ushort_t;

__device__ __forceinline__ void unpack2(unsigned u, float& a, float& b) {
    union { unsigned x; float f; } lo, hi;
    lo.x = u << 16; hi.x = u & 0xffff0000u;
    a = lo.f; b = hi.f;
}
__device__ __forceinline__ void unpack8(uint4 u, float* f) {
    unpack2(u.x, f[0], f[1]); unpack2(u.y, f[2], f[3]);
    unpack2(u.z, f[4], f[5]); unpack2(u.w, f[6], f[7]);
}

// ---------------- kernel A: transpose 4 weight matrices into ws ----------------
__global__ void transpose_kernel(const float* __restrict__ Wq, const float* __restrict__ Wk,
                                 const float* __restrict__ Wv, const float* __restrict__ Wo,
                                 float* __restrict__ wt)
{
    int idx = blockIdx.x * 256 + threadIdx.x;     // 0..65535
    int w = idx >> 14, rem = idx & 16383;
    int row = rem >> 7, col = rem & 127;          // reading W[row*128+col] coalesced
    const float* W = (w == 0) ? Wq : (w == 1) ? Wk : (w == 2) ? Wv : Wo;
    wt[w * 16384 + col * HID + row] = W[rem];     // WT[i][j] = W[j][i]
}

// ---------------- kernel B: QKV projection; K,V stored bf16 ----------------
__global__ __launch_bounds__(128) void qkv_kernel(
    const float* __restrict__ x, const float* __restrict__ WqT,
    const float* __restrict__ WkT, const float* __restrict__ WvT,
    const float* __restrict__ bq, const float* __restrict__ bk,
    const float* __restrict__ bv, float* __restrict__ Qm,
    __hip_bfloat16* __restrict__ Kb, __hip_bfloat16* __restrict__ Vb)
{
    __shared__ float xs[16 * HID];
    const int j = threadIdx.x;
    const int r0 = blockIdx.x * 16;
    const float4* xg = (const float4*)(x + (size_t)r0 * HID);
    float4* xl = (float4*)xs;
    for (int i = j; i < 16 * HID / 4; i += 128) xl[i] = xg[i];
    __syncthreads();
    float aq[16], ak[16], av[16];
#pragma unroll
    for (int r = 0; r < 16; ++r) { aq[r] = 0.f; ak[r] = 0.f; av[r] = 0.f; }
    for (int i = 0; i < HID; ++i) {
        float wq = WqT[i * HID + j], wk = WkT[i * HID + j], wv = WvT[i * HID + j];
#pragma unroll
        for (int r = 0; r < 16; ++r) {
            float xv = xs[r * HID + i];
            aq[r] = fmaf(xv, wq, aq[r]);
            ak[r] = fmaf(xv, wk, ak[r]);
            av[r] = fmaf(xv, wv, av[r]);
        }
    }
    float bqv = bq[j], bkv = bk[j], bvv = bv[j];
#pragma unroll
    for (int r = 0; r < 16; ++r) {
        Qm[(size_t)(r0 + r) * HID + j] = aq[r] + bqv;
        Kb[(size_t)(r0 + r) * HID + j] = __float2bfloat16(ak[r] + bkv);
        Vb[(size_t)(r0 + r) * HID + j] = __float2bfloat16(av[r] + bvv);
    }
}

// ---------------- kernel C: fused flash attention ----------------
// grid 256 blocks (TQ=8 query rows each), 256 threads
__global__ __launch_bounds__(256) void attn_kernel(
    const float* __restrict__ Qm, const __hip_bfloat16* __restrict__ Kb,
    const __hip_bfloat16* __restrict__ Vb, const float* __restrict__ bias,
    const unsigned char* __restrict__ mask, float* __restrict__ O)
{
    __shared__ float qs[TQ * QROW];            // 5 KB, padded layout
    __shared__ float S[TK * SROW];             // 16 KB, [m][h][r]
    __shared__ float mrun[TQ * HEADS], lrun[TQ * HEADS], alpha_s[TQ * HEADS];
    __shared__ float pmax[4 * TQ * HEADS], psum[4 * TQ * HEADS];

    const int t = threadIdx.x;
    const int n0 = blockIdx.x * TQ;

    // roles
    const int sc_mp = t >> 3;          // 0..31 -> m pair
    const int sc_h  = t & 7;
    const int rd_rh = t & 63;          // (r,h) pair index
    const int rd_r  = rd_rh >> 3;
    const int rd_h  = rd_rh & 7;
    const int rd_q  = t >> 6;          // quarter of m-tile
    const int pv_hd = t & 127;
    const int pv_half = t >> 7;
    const int pv_h = pv_hd >> 4;
    const int pv_d = pv_hd & 15;

    if (t < TQ * HEADS) { mrun[t] = -INFINITY; lrun[t] = 0.0f; }
    {   // load q tile (1024 floats) into padded/swizzled layout
        int r = t >> 5, c = t & 31;            // c = float4 index within row
        int h = c >> 2, dg = c & 3;
        float4 v = ((const float4*)(Qm + (size_t)n0 * HID))[t];
        float* dst = &qs[r * QROW + h * 20 + dg * 4];
        dst[0] = v.x; dst[1] = v.y; dst[2] = v.z; dst[3] = v.w;
    }
    float acc[TQ];
#pragma unroll
    for (int r = 0; r < TQ; ++r) acc[r] = 0.0f;
    __syncthreads();

    for (int kt = 0; kt < NSEQ / TK; ++kt) {
        const int m0 = kt * TK;
        // ---- phase 1: scores (each thread: 2 m-rows, 1 head, 8 q-rows) ----
        {
            const int m1 = m0 + sc_mp * 2;
            float bb0[TQ], bb1[TQ];
            {
                const float* bp = bias + ((size_t)n0 * NSEQ + m1) * HEADS + sc_h;
#pragma unroll
                for (int r = 0; r < TQ; ++r) {
                    bb0[r] = bp[(size_t)r * (NSEQ * HEADS)];
                    bb1[r] = bp[(size_t)r * (NSEQ * HEADS) + HEADS];
                }
            }
            const ushort_t* kp = (const ushort_t*)Kb + (size_t)m1 * HID + sc_h * HD;
            uint4 ka = *(const uint4*)kp;
            uint4 kb2 = *(const uint4*)(kp + 8);
            uint4 kc = *(const uint4*)(kp + HID);
            uint4 kd = *(const uint4*)(kp + HID + 8);
            float k0[16], k1[16];
            unpack8(ka, k0); unpack8(kb2, k0 + 8);
            unpack8(kc, k1); unpack8(kd, k1 + 8);
            const bool msk0 = mask[m1] != 0;
            const bool msk1 = mask[m1 + 1] != 0;
            float sb0[TQ], sb1[TQ];
#pragma unroll
            for (int r = 0; r < TQ; ++r) {
                const float* qr = &qs[r * QROW + sc_h * 20];
                float qf[16];
                *(float4*)&qf[0]  = *(const float4*)(qr);
                *(float4*)&qf[4]  = *(const float4*)(qr + 4);
                *(float4*)&qf[8]  = *(const float4*)(qr + 8);
                *(float4*)&qf[12] = *(const float4*)(qr + 12);
                float d0 = 0.f, d1 = 0.f;
#pragma unroll
                for (int i = 0; i < 16; ++i) {
                    d0 = fmaf(qf[i], k0[i], d0);
                    d1 = fmaf(qf[i], k1[i], d1);
                }
                float s0 = fmaf(d0, SCALE, bb0[r]);
                float s1 = fmaf(d1, SCALE, bb1[r]);
                if (msk0) s0 = -INFINITY;
                if (msk1) s1 = -INFINITY;
                sb0[r] = s0; sb1[r] = s1;
            }
            float4* w0 = (float4*)&S[(2 * sc_mp) * SROW + sc_h * 8];
            w0[0] = make_float4(sb0[0], sb0[1], sb0[2], sb0[3]);
            w0[1] = make_float4(sb0[4], sb0[5], sb0[6], sb0[7]);
            float4* w1 = (float4*)&S[(2 * sc_mp + 1) * SROW + sc_h * 8];
            w1[0] = make_float4(sb1[0], sb1[1], sb1[2], sb1[3]);
            w1[1] = make_float4(sb1[4], sb1[5], sb1[6], sb1[7]);
        }
        __syncthreads();
        // ---- phase 2a: partial max over m (per (r,h), quarter-split) ----
        {
            const int base = rd_h * 8 + rd_r;
            float mx = -INFINITY;
#pragma unroll
            for (int i = 0; i < 16; ++i)
                mx = fmaxf(mx, S[(rd_q * 16 + i) * SROW + base]);
            pmax[rd_q * 64 + rd_rh] = mx;
        }
        __syncthreads();
        // ---- phase 2b: running max + alpha ----
        if (t < 64) {
            float mold = mrun[t];
            float mx = fmaxf(fmaxf(pmax[t], pmax[64 + t]), fmaxf(pmax[128 + t], pmax[192 + t]));
            float mnew = fmaxf(mold, mx);
            float a = (mnew == -INFINITY) ? 1.0f : __expf(mold - mnew);
            alpha_s[t] = a;
            mrun[t] = mnew;
        }
        __syncthreads();
        // ---- phase 2c: exponentiate in place + partial sums ----
        {
            const float mnew = mrun[rd_rh];
            const int base = rd_h * 8 + rd_r;
            float sum = 0.0f;
#pragma unroll
            for (int i = 0; i < 16; ++i) {
                int idx = (rd_q * 16 + i) * SROW + base;
                float s = S[idx];
                float e = (s == -INFINITY) ? 0.0f : __expf(s - mnew);
                S[idx] = e;
                sum += e;
            }
            psum[rd_q * 64 + rd_rh] = sum;
        }
        __syncthreads();
        // ---- phase 2d + 3: l update, acc rescale, PV ----
        if (t < 64)
            lrun[t] = lrun[t] * alpha_s[t] + (psum[t] + psum[64 + t] + psum[128 + t] + psum[192 + t]);
        {
#pragma unroll
            for (int r = 0; r < TQ; ++r) acc[r] *= alpha_s[r * 8 + pv_h];
            const ushort_t* vp = (const ushort_t*)Vb + (size_t)(m0 + pv_half * 32) * HID + pv_h * HD + pv_d;
#pragma unroll 4
            for (int mm = 0; mm < 32; ++mm) {
                union { unsigned x; float f; } cv;
                cv.x = ((unsigned)vp[(size_t)mm * HID]) << 16;
                const float v = cv.f;
                const float4 p0 = *(const float4*)&S[(pv_half * 32 + mm) * SROW + pv_h * 8];
                const float4 p1 = *(const float4*)&S[(pv_half * 32 + mm) * SROW + pv_h * 8 + 4];
                acc[0] = fmaf(p0.x, v, acc[0]); acc[1] = fmaf(p0.y, v, acc[1]);
                acc[2] = fmaf(p0.z, v, acc[2]); acc[3] = fmaf(p0.w, v, acc[3]);
                acc[4] = fmaf(p1.x, v, acc[4]); acc[5] = fmaf(p1.y, v, acc[5]);
                acc[6] = fmaf(p1.z, v, acc[6]); acc[7] = fmaf(p1.w, v, acc[7]);
            }
        }
        __syncthreads();
    }

    // ---- epilogue: merge halves, divide by l, write O ----
#pragma unroll
    for (int r = 0; r < TQ; ++r)
        S[(r * HID + pv_hd) * 2 + pv_half] = acc[r];
    __syncthreads();
    if (t < HID) {
#pragma unroll
        for (int r = 0; r < TQ; ++r) {
            float s = S[(r * HID + t) * 2] + S[(r * HID + t) * 2 + 1];
            float l = lrun[r * 8 + (t >> 4)];
            O[(size_t)(n0 + r) * HID + t] = s / l;
        }
    }
}

// ---------------- kernel D: output projection ----------------
__global__ __launch_bounds__(128) void proj_kernel(
    const float* __restrict__ O, const float* __restrict__ WoT,
    const float* __restrict__ bo, float* __restrict__ out)
{
    __shared__ float xs[16 * HID];
    const int j = threadIdx.x;
    const int r0 = blockIdx.x * 16;
    const float4* og = (const float4*)(O + (size_t)r0 * HID);
    float4* xl = (float4*)xs;
    for (int i = j; i < 16 * HID / 4; i += 128) xl[i] = og[i];
    __syncthreads();
    float acc[16];
#pragma unroll
    for (int r = 0; r < 16; ++r) acc[r] = 0.f;
    for (int i = 0; i < HID; ++i) {
        float w = WoT[i * HID + j];
#pragma unroll
        for (int r = 0; r < 16; ++r) acc[r] = fmaf(xs[r * HID + i], w, acc[r]);
    }
    float b = bo[j];
#pragma unroll
    for (int r = 0; r < 16; ++r)
        out[(size_t)(r0 + r) * HID + j] = acc[r] + b;
}

extern "C" void kernel_launch(void* const* d_in, const int* in_sizes, int n_in,
                              void* d_out, int out_size, void* d_ws, size_t ws_size,
                              hipStream_t stream) {
    const float* x    = (const float*)d_in[0];
    const float* bias = (const float*)d_in[1];
    const unsigned char* mask = (const unsigned char*)d_in[2];
    const float* Wq = (const float*)d_in[3];
    const float* bq = (const float*)d_in[4];
    const float* Wk = (const float*)d_in[5];
    const float* bk = (const float*)d_in[6];
    const float* Wv = (const float*)d_in[7];
    const float* bv = (const float*)d_in[8];
    const float* Wo = (const float*)d_in[9];
    const float* bo = (const float*)d_in[10];
    float* out = (float*)d_out;

    float* w = (float*)d_ws;
    // ws layout (float offsets):
    float* WqT = w;                 // 16384
    float* WkT = w + 16384;
    float* WvT = w + 32768;
    float* WoT = w + 49152;
    float* Qm  = w + 65536;         // 262144 fp32
    __hip_bfloat16* Kb = (__hip_bfloat16*)(w + 327680);  // 262144 bf16
    __hip_bfloat16* Vb = (__hip_bfloat16*)(w + 458752);  // 262144 bf16
    float* O   = w + 589824;        // 262144 fp32  (total ~3.25 MB)

    transpose_kernel<<<256, 256, 0, stream>>>(Wq, Wk, Wv, Wo, w);
    qkv_kernel<<<NSEQ / 16, 128, 0, stream>>>(x, WqT, WkT, WvT, bq, bk, bv, Qm, Kb, Vb);
    attn_kernel<<<NSEQ / TQ, 256, 0, stream>>>(Qm, Kb, Vb, bias, mask, O);
    proj_kernel<<<NSEQ / 16, 128, 0, stream>>>(O, WoT, bo, out);
}

// Round 2
// 287.000 us; speedup vs baseline: 1.3974x; 1.3974x over previous
//
#include <hip/hip_runtime.h>
#include <hip/hip_bf16.h>

#define NSEQ 2048
#define HID 128
#define HEADS 8
#define HD 16
#define SCALE 0.25f
#define TQ 8
#define TK 64
#define SPLIT 4
#define KT_PER (NSEQ / TK / SPLIT)   // 8 tiles per block
#define QROW 160            // padded q row stride (floats): 8 chunks of 20
#define SROW 68             // padded S row stride (floats)

typedef unsigned short ushort_t;

__device__ __forceinline__ void unpack2(unsigned u, float& a, float& b) {
    union { unsigned x; float f; } lo, hi;
    lo.x = u << 16; hi.x = u & 0xffff0000u;
    a = lo.f; b = hi.f;
}
__device__ __forceinline__ void unpack8(uint4 u, float* f) {
    unpack2(u.x, f[0], f[1]); unpack2(u.y, f[2], f[3]);
    unpack2(u.z, f[4], f[5]); unpack2(u.w, f[6], f[7]);
}

// ---------------- kernel A: transpose 4 weight matrices into ws ----------------
__global__ void transpose_kernel(const float* __restrict__ Wq, const float* __restrict__ Wk,
                                 const float* __restrict__ Wv, const float* __restrict__ Wo,
                                 float* __restrict__ wt)
{
    int idx = blockIdx.x * 256 + threadIdx.x;     // 0..65535
    int w = idx >> 14, rem = idx & 16383;
    int row = rem >> 7, col = rem & 127;
    const float* W = (w == 0) ? Wq : (w == 1) ? Wk : (w == 2) ? Wv : Wo;
    wt[w * 16384 + col * HID + row] = W[rem];     // WT[i][j] = W[j][i]
}

// ---------------- kernel B: QKV projection; K,V stored bf16 ----------------
// grid 256 blocks x 128 threads, 8 rows per block
__global__ __launch_bounds__(128) void qkv_kernel(
    const float* __restrict__ x, const float* __restrict__ WqT,
    const float* __restrict__ WkT, const float* __restrict__ WvT,
    const float* __restrict__ bq, const float* __restrict__ bk,
    const float* __restrict__ bv, float* __restrict__ Qm,
    __hip_bfloat16* __restrict__ Kb, __hip_bfloat16* __restrict__ Vb)
{
    __shared__ float xs[8 * HID];
    const int j = threadIdx.x;
    const int r0 = blockIdx.x * 8;
    const float4* xg = (const float4*)(x + (size_t)r0 * HID);
    float4* xl = (float4*)xs;
    for (int i = j; i < 8 * HID / 4; i += 128) xl[i] = xg[i];
    __syncthreads();
    float aq[8], ak[8], av[8];
#pragma unroll
    for (int r = 0; r < 8; ++r) { aq[r] = 0.f; ak[r] = 0.f; av[r] = 0.f; }
    for (int i = 0; i < HID; ++i) {
        float wq = WqT[i * HID + j], wk = WkT[i * HID + j], wv = WvT[i * HID + j];
#pragma unroll
        for (int r = 0; r < 8; ++r) {
            float xv = xs[r * HID + i];
            aq[r] = fmaf(xv, wq, aq[r]);
            ak[r] = fmaf(xv, wk, ak[r]);
            av[r] = fmaf(xv, wv, av[r]);
        }
    }
    float bqv = bq[j], bkv = bk[j], bvv = bv[j];
#pragma unroll
    for (int r = 0; r < 8; ++r) {
        Qm[(size_t)(r0 + r) * HID + j] = aq[r] + bqv;
        Kb[(size_t)(r0 + r) * HID + j] = __float2bfloat16(ak[r] + bkv);
        Vb[(size_t)(r0 + r) * HID + j] = __float2bfloat16(av[r] + bvv);
    }
}

// ---------------- kernel C: fused attention, split-K, no online softmax ----------------
// grid 256*SPLIT blocks x 256 threads; block = TQ=8 query rows, 512 keys
__global__ __launch_bounds__(256, 4) void attn_kernel(
    const float* __restrict__ Qm, const __hip_bfloat16* __restrict__ Kb,
    const __hip_bfloat16* __restrict__ Vb, const float* __restrict__ bias,
    const unsigned char* __restrict__ mask, float* __restrict__ Op,
    float* __restrict__ Lp)
{
    __shared__ float qs[TQ * QROW];            // 5 KB
    __shared__ float S[TK * SROW];             // 17.4 KB (exp'd scores)
    __shared__ float wl[4 * TQ * HEADS];       // per-wave l partials

    const int t = threadIdx.x;
    const int qb = blockIdx.x & 255;
    const int sp = blockIdx.x >> 8;
    const int n0 = qb * TQ;

    // roles
    const int sc_mp = t >> 3;          // 0..31 -> m pair
    const int sc_h  = t & 7;
    const int pv_hd = t & 127;
    const int pv_half = t >> 7;
    const int pv_h = pv_hd >> 4;
    const int pv_d = pv_hd & 15;

    {   // load q tile (1024 floats) into padded layout
        int r = t >> 5, c = t & 31;
        int h = c >> 2, dg = c & 3;
        float4 v = ((const float4*)(Qm + (size_t)n0 * HID))[t];
        float* dst = &qs[r * QROW + h * 20 + dg * 4];
        dst[0] = v.x; dst[1] = v.y; dst[2] = v.z; dst[3] = v.w;
    }
    float acc[TQ];
    float lsum[TQ];
#pragma unroll
    for (int r = 0; r < TQ; ++r) { acc[r] = 0.0f; lsum[r] = 0.0f; }
    __syncthreads();

    for (int kt = 0; kt < KT_PER; ++kt) {
        const int m0 = (sp * KT_PER + kt) * TK;
        // ---- phase 1: scores + exp, write P into S ----
        {
            const int m1 = m0 + sc_mp * 2;
            float bb0[TQ], bb1[TQ];
            {
                const float* bp = bias + ((size_t)n0 * NSEQ + m1) * HEADS + sc_h;
#pragma unroll
                for (int r = 0; r < TQ; ++r) {
                    bb0[r] = __builtin_nontemporal_load(bp + (size_t)r * (NSEQ * HEADS));
                    bb1[r] = __builtin_nontemporal_load(bp + (size_t)r * (NSEQ * HEADS) + HEADS);
                }
            }
            const ushort_t* kp = (const ushort_t*)Kb + (size_t)m1 * HID + sc_h * HD;
            uint4 ka = *(const uint4*)kp;
            uint4 kb2 = *(const uint4*)(kp + 8);
            uint4 kc = *(const uint4*)(kp + HID);
            uint4 kd = *(const uint4*)(kp + HID + 8);
            float k0[16], k1[16];
            unpack8(ka, k0); unpack8(kb2, k0 + 8);
            unpack8(kc, k1); unpack8(kd, k1 + 8);
            const bool msk0 = mask[m1] != 0;
            const bool msk1 = mask[m1 + 1] != 0;
#pragma unroll
            for (int rg = 0; rg < 2; ++rg) {      // two groups of 4 rows
                float e0[4], e1[4];
#pragma unroll
                for (int rr = 0; rr < 4; ++rr) {
                    const int r = rg * 4 + rr;
                    const float* qr = &qs[r * QROW + sc_h * 20];
                    float qf[16];
                    *(float4*)&qf[0]  = *(const float4*)(qr);
                    *(float4*)&qf[4]  = *(const float4*)(qr + 4);
                    *(float4*)&qf[8]  = *(const float4*)(qr + 8);
                    *(float4*)&qf[12] = *(const float4*)(qr + 12);
                    float d0 = 0.f, d1 = 0.f;
#pragma unroll
                    for (int i = 0; i < 16; ++i) {
                        d0 = fmaf(qf[i], k0[i], d0);
                        d1 = fmaf(qf[i], k1[i], d1);
                    }
                    float s0 = fmaf(d0, SCALE, bb0[r]);
                    float s1 = fmaf(d1, SCALE, bb1[r]);
                    if (msk0) s0 = -INFINITY;
                    if (msk1) s1 = -INFINITY;
                    float ee0 = __expf(s0);
                    float ee1 = __expf(s1);
                    lsum[r] += ee0 + ee1;
                    e0[rr] = ee0; e1[rr] = ee1;
                }
                *(float4*)&S[(2 * sc_mp) * SROW + sc_h * 8 + rg * 4] =
                    make_float4(e0[0], e0[1], e0[2], e0[3]);
                *(float4*)&S[(2 * sc_mp + 1) * SROW + sc_h * 8 + rg * 4] =
                    make_float4(e1[0], e1[1], e1[2], e1[3]);
            }
        }
        __syncthreads();
        // ---- phase 2: PV ----
        {
            const ushort_t* vp = (const ushort_t*)Vb + (size_t)(m0 + pv_half * 32) * HID + pv_h * HD + pv_d;
#pragma unroll 4
            for (int mm = 0; mm < 32; ++mm) {
                union { unsigned x; float f; } cv;
                cv.x = ((unsigned)vp[(size_t)mm * HID]) << 16;
                const float v = cv.f;
                const float4 p0 = *(const float4*)&S[(pv_half * 32 + mm) * SROW + pv_h * 8];
                const float4 p1 = *(const float4*)&S[(pv_half * 32 + mm) * SROW + pv_h * 8 + 4];
                acc[0] = fmaf(p0.x, v, acc[0]); acc[1] = fmaf(p0.y, v, acc[1]);
                acc[2] = fmaf(p0.z, v, acc[2]); acc[3] = fmaf(p0.w, v, acc[3]);
                acc[4] = fmaf(p1.x, v, acc[4]); acc[5] = fmaf(p1.y, v, acc[5]);
                acc[6] = fmaf(p1.z, v, acc[6]); acc[7] = fmaf(p1.w, v, acc[7]);
            }
        }
        __syncthreads();
    }

    // ---- epilogue ----
    // reduce lsum over sc_mp within wave (lanes differ in bits 3..5 of lane id)
#pragma unroll
    for (int r = 0; r < TQ; ++r) {
        lsum[r] += __shfl_xor(lsum[r], 8);
        lsum[r] += __shfl_xor(lsum[r], 16);
        lsum[r] += __shfl_xor(lsum[r], 32);
    }
    const int wid = t >> 6;
    if ((t & 63) < 8) {
#pragma unroll
        for (int r = 0; r < TQ; ++r)
            wl[wid * 64 + r * 8 + sc_h] = lsum[r];
    }
    // stash acc halves in S for merge
#pragma unroll
    for (int r = 0; r < TQ; ++r)
        S[r * 256 + pv_hd * 2 + pv_half] = acc[r];
    __syncthreads();
    if (t < 64) {
        const int r = t >> 3, h = t & 7;
        float l = wl[t] + wl[64 + t] + wl[128 + t] + wl[192 + t];
        Lp[((size_t)sp * NSEQ + n0 + r) * HEADS + h] = l;
    }
    if (t < 128) {
#pragma unroll
        for (int r = 0; r < TQ; ++r) {
            float s = S[r * 256 + t * 2] + S[r * 256 + t * 2 + 1];
            Op[((size_t)sp * NSEQ + n0 + r) * HID + t] = s;
        }
    }
}

// ---------------- kernel D: combine splits + output projection ----------------
// grid 256 blocks x 128 threads, 8 rows per block
__global__ __launch_bounds__(128) void proj_kernel(
    const float* __restrict__ Op, const float* __restrict__ Lp,
    const float* __restrict__ WoT, const float* __restrict__ bo,
    float* __restrict__ out)
{
    __shared__ float xs[8 * HID];
    const int j = threadIdx.x;
    const int r0 = blockIdx.x * 8;
    const int hh = j >> 4;
#pragma unroll
    for (int r = 0; r < 8; ++r) {
        const size_t n = r0 + r;
        float s = 0.f, l = 0.f;
#pragma unroll
        for (int sp = 0; sp < SPLIT; ++sp) {
            s += Op[((size_t)sp * NSEQ + n) * HID + j];
            l += Lp[((size_t)sp * NSEQ + n) * HEADS + hh];
        }
        xs[r * HID + j] = s / l;
    }
    __syncthreads();
    float acc[8];
#pragma unroll
    for (int r = 0; r < 8; ++r) acc[r] = 0.f;
    for (int i = 0; i < HID; ++i) {
        float w = WoT[i * HID + j];
#pragma unroll
        for (int r = 0; r < 8; ++r) acc[r] = fmaf(xs[r * HID + i], w, acc[r]);
    }
    float b = bo[j];
#pragma unroll
    for (int r = 0; r < 8; ++r)
        out[(size_t)(r0 + r) * HID + j] = acc[r] + b;
}

extern "C" void kernel_launch(void* const* d_in, const int* in_sizes, int n_in,
                              void* d_out, int out_size, void* d_ws, size_t ws_size,
                              hipStream_t stream) {
    const float* x    = (const float*)d_in[0];
    const float* bias = (const float*)d_in[1];
    const unsigned char* mask = (const unsigned char*)d_in[2];
    const float* Wq = (const float*)d_in[3];
    const float* bq = (const float*)d_in[4];
    const float* Wk = (const float*)d_in[5];
    const float* bk = (const float*)d_in[6];
    const float* Wv = (const float*)d_in[7];
    const float* bv = (const float*)d_in[8];
    const float* Wo = (const float*)d_in[9];
    const float* bo = (const float*)d_in[10];
    float* out = (float*)d_out;

    float* w = (float*)d_ws;
    // ws layout (float offsets):
    float* WqT = w;                                     // 16384
    float* WkT = w + 16384;
    float* WvT = w + 32768;
    float* WoT = w + 49152;
    float* Qm  = w + 65536;                             // 262144 fp32
    __hip_bfloat16* Kb = (__hip_bfloat16*)(w + 327680); // 262144 bf16
    __hip_bfloat16* Vb = (__hip_bfloat16*)(w + 458752); // 262144 bf16
    float* Op  = w + 589824;                            // SPLIT*262144 fp32 (4 MB)
    float* Lp  = w + 589824 + SPLIT * NSEQ * HID;       // SPLIT*2048*8 fp32
    // total ~6.6 MB

    transpose_kernel<<<256, 256, 0, stream>>>(Wq, Wk, Wv, Wo, w);
    qkv_kernel<<<NSEQ / 8, 128, 0, stream>>>(x, WqT, WkT, WvT, bq, bk, bv, Qm, Kb, Vb);
    attn_kernel<<<256 * SPLIT, 256, 0, stream>>>(Qm, Kb, Vb, bias, mask, Op, Lp);
    proj_kernel<<<NSEQ / 8, 128, 0, stream>>>(Op, Lp, WoT, bo, out);
}

// Round 3
// 242.947 us; speedup vs baseline: 1.6508x; 1.1813x over previous
//
#include <hip/hip_runtime.h>
#include <hip/hip_bf16.h>

#define NSEQ 2048
#define HID 128
#define HEADS 8
#define HD 16
#define SCALE 0.25f
#define TQ 16
#define TK 64
#define SPLIT 8
#define KT_PER (NSEQ / TK / SPLIT)   // 4 tiles per block
#define QROW 160            // padded q row stride (floats): 8 chunks of 20
#define PM_W 36             // P row stride in 32-bit words (64 keys = 32 words + pad)
#define PH_W (16 * PM_W + 4)  // 580: P head stride in words
// LDS P/obuf pool: 8 * 580 = 4640 words

typedef unsigned short ushort_t;
typedef __attribute__((ext_vector_type(8))) short short8;
typedef __attribute__((ext_vector_type(4))) float floatx4;

__device__ __forceinline__ void unpack2(unsigned u, float& a, float& b) {
    union { unsigned x; float f; } lo, hi;
    lo.x = u << 16; hi.x = u & 0xffff0000u;
    a = lo.f; b = hi.f;
}
__device__ __forceinline__ void unpack8(uint4 u, float* f) {
    unpack2(u.x, f[0], f[1]); unpack2(u.y, f[2], f[3]);
    unpack2(u.z, f[4], f[5]); unpack2(u.w, f[6], f[7]);
}
__device__ __forceinline__ unsigned pack_bf16x2(float a, float b) {
    __hip_bfloat16 ba = __float2bfloat16(a);
    __hip_bfloat16 bb = __float2bfloat16(b);
    return (unsigned)*(ushort_t*)&ba | ((unsigned)*(ushort_t*)&bb << 16);
}

// ---------------- kernel A: transpose 4 weight matrices into ws ----------------
__global__ void transpose_kernel(const float* __restrict__ Wq, const float* __restrict__ Wk,
                                 const float* __restrict__ Wv, const float* __restrict__ Wo,
                                 float* __restrict__ wt)
{
    int idx = blockIdx.x * 256 + threadIdx.x;     // 0..65535
    int w = idx >> 14, rem = idx & 16383;
    int row = rem >> 7, col = rem & 127;
    const float* W = (w == 0) ? Wq : (w == 1) ? Wk : (w == 2) ? Wv : Wo;
    wt[w * 16384 + col * HID + row] = W[rem];     // WT[i][j] = W[j][i]
}

// ---------------- kernel B: QKV projection, one matrix per block-range ----------------
// grid 768 blocks x 128 threads; blocks [0,256)->Q fp32, [256,512)->K bf16 rows,
// [512,768)->V bf16 TRANSPOSED (Vt[j][n], j = h*16+d)
__global__ __launch_bounds__(128) void qkv_kernel(
    const float* __restrict__ x, const float* __restrict__ WqT,
    const float* __restrict__ WkT, const float* __restrict__ WvT,
    const float* __restrict__ bq, const float* __restrict__ bk,
    const float* __restrict__ bv, float* __restrict__ Qm,
    __hip_bfloat16* __restrict__ Kb, __hip_bfloat16* __restrict__ Vt)
{
    __shared__ float xs[8 * HID];
    const int j = threadIdx.x;
    const int mat = blockIdx.x >> 8;
    const int rb = blockIdx.x & 255;
    const int r0 = rb * 8;
    const float* WT = (mat == 0) ? WqT : (mat == 1) ? WkT : WvT;
    const float* bb = (mat == 0) ? bq : (mat == 1) ? bk : bv;
    const float4* xg = (const float4*)(x + (size_t)r0 * HID);
    float4* xl = (float4*)xs;
    for (int i = j; i < 8 * HID / 4; i += 128) xl[i] = xg[i];
    __syncthreads();
    float acc[8];
#pragma unroll
    for (int r = 0; r < 8; ++r) acc[r] = 0.f;
#pragma unroll 4
    for (int i = 0; i < HID; ++i) {
        float w = WT[i * HID + j];
#pragma unroll
        for (int r = 0; r < 8; ++r) acc[r] = fmaf(xs[r * HID + i], w, acc[r]);
    }
    float bv_ = bb[j];
#pragma unroll
    for (int r = 0; r < 8; ++r) acc[r] += bv_;
    if (mat == 0) {
#pragma unroll
        for (int r = 0; r < 8; ++r) Qm[(size_t)(r0 + r) * HID + j] = acc[r];
    } else if (mat == 1) {
#pragma unroll
        for (int r = 0; r < 8; ++r) Kb[(size_t)(r0 + r) * HID + j] = __float2bfloat16(acc[r]);
    } else {
        // transposed store: Vt[j][r0..r0+7], 16B contiguous per thread
        unsigned u[4];
#pragma unroll
        for (int p = 0; p < 4; ++p) u[p] = pack_bf16x2(acc[2 * p], acc[2 * p + 1]);
        *(uint4*)((ushort_t*)Vt + (size_t)j * NSEQ + r0) = make_uint4(u[0], u[1], u[2], u[3]);
    }
}

// ---------------- kernel C: fused attention, split-K, MFMA PV ----------------
// grid 128*SPLIT blocks x 256 threads; block = TQ=16 query rows, 256 keys
__global__ __launch_bounds__(256, 4) void attn_kernel(
    const float* __restrict__ Qm, const __hip_bfloat16* __restrict__ Kb,
    const __hip_bfloat16* __restrict__ Vt, const float* __restrict__ bias,
    const unsigned char* __restrict__ mask, float* __restrict__ Op,
    float* __restrict__ Lp)
{
    __shared__ float qs[TQ * QROW];      // 10.2 KB padded fp32 q
    __shared__ float Pbuf[8 * PH_W];     // 18.1 KB: P bf16 tile; reused as obuf in epilogue
    __shared__ float wl[4 * TQ * HEADS]; // 2 KB per-wave l partials

    const int t = threadIdx.x;
    const int lane = t & 63;
    const int wid = t >> 6;
    const int qb = blockIdx.x & 127;
    const int sp = blockIdx.x >> 7;
    const int n0 = qb * TQ;

    // score roles
    const int sc_mp = t >> 3;          // 0..31 -> key pair
    const int sc_h  = t & 7;
    // PV roles
    const int kk = wid & 1;            // K-half of the 64-key tile
    const int hbase = (wid >> 1) * 4;  // 4 heads per wave-pair
    const int frag_m = lane & 15;
    const int frag_q = lane >> 4;

    {   // load q tile (2048 floats) into padded layout
        for (int idx = t; idx < 512; idx += 256) {
            int r = idx >> 5, c = idx & 31;
            int h = c >> 2, dg = c & 3;
            float4 v = ((const float4*)(Qm + (size_t)n0 * HID))[idx];
            *(float4*)&qs[r * QROW + h * 20 + dg * 4] = v;
        }
    }
    floatx4 acc[4];
#pragma unroll
    for (int hh = 0; hh < 4; ++hh) acc[hh] = (floatx4){0.f, 0.f, 0.f, 0.f};
    float lsum[TQ];
#pragma unroll
    for (int r = 0; r < TQ; ++r) lsum[r] = 0.0f;
    __syncthreads();

    for (int kt = 0; kt < KT_PER; ++kt) {
        const int m0 = (sp * KT_PER + kt) * TK;
        // ---- phase 1: fp32 scores + exp -> P (bf16) ----
        {
            const int m1 = m0 + sc_mp * 2;
            const ushort_t* kp = (const ushort_t*)Kb + (size_t)m1 * HID + sc_h * HD;
            uint4 ka = *(const uint4*)kp;
            uint4 kb2 = *(const uint4*)(kp + 8);
            uint4 kc = *(const uint4*)(kp + HID);
            uint4 kd = *(const uint4*)(kp + HID + 8);
            float k0[16], k1[16];
            unpack8(ka, k0); unpack8(kb2, k0 + 8);
            unpack8(kc, k1); unpack8(kd, k1 + 8);
            const bool msk0 = mask[m1] != 0;
            const bool msk1 = mask[m1 + 1] != 0;
            unsigned* Pw = (unsigned*)Pbuf;
#pragma unroll
            for (int rg = 0; rg < 2; ++rg) {      // two groups of 8 rows
                float bb0[8], bb1[8];
                const float* bp = bias + (((size_t)(n0 + rg * 8)) * NSEQ + m1) * HEADS + sc_h;
#pragma unroll
                for (int rr = 0; rr < 8; ++rr) {
                    bb0[rr] = __builtin_nontemporal_load(bp + (size_t)rr * (NSEQ * HEADS));
                    bb1[rr] = __builtin_nontemporal_load(bp + (size_t)rr * (NSEQ * HEADS) + HEADS);
                }
#pragma unroll
                for (int rr = 0; rr < 8; ++rr) {
                    const int r = rg * 8 + rr;
                    const float* qr = &qs[r * QROW + sc_h * 20];
                    float qf[16];
                    *(float4*)&qf[0]  = *(const float4*)(qr);
                    *(float4*)&qf[4]  = *(const float4*)(qr + 4);
                    *(float4*)&qf[8]  = *(const float4*)(qr + 8);
                    *(float4*)&qf[12] = *(const float4*)(qr + 12);
                    float d0 = 0.f, d1 = 0.f;
#pragma unroll
                    for (int i = 0; i < 16; ++i) {
                        d0 = fmaf(qf[i], k0[i], d0);
                        d1 = fmaf(qf[i], k1[i], d1);
                    }
                    float s0 = fmaf(d0, SCALE, bb0[rr]);
                    float s1 = fmaf(d1, SCALE, bb1[rr]);
                    if (msk0) s0 = -INFINITY;
                    if (msk1) s1 = -INFINITY;
                    float e0 = __expf(s0);
                    float e1 = __expf(s1);
                    lsum[r] += e0 + e1;
                    Pw[sc_h * PH_W + r * PM_W + sc_mp] = pack_bf16x2(e0, e1);
                }
            }
        }
        __syncthreads();
        // ---- phase 2: PV via MFMA ----
        {
            const unsigned* Pw = (const unsigned*)Pbuf;
#pragma unroll
            for (int hh = 0; hh < 4; ++hh) {
                const int h = hbase + hh;
                const ushort_t* vrow = (const ushort_t*)Vt +
                    ((size_t)(h * HD + frag_m)) * NSEQ + m0 + kk * 32 + frag_q * 8;
                short8 bfrag = *(const short8*)vrow;
                short8 afrag = *(const short8*)&Pw[h * PH_W + frag_m * PM_W + kk * 16 + frag_q * 4];
                acc[hh] = __builtin_amdgcn_mfma_f32_16x16x32_bf16(afrag, bfrag, acc[hh], 0, 0, 0);
            }
        }
        __syncthreads();
    }

    // ---- epilogue ----
    // reduce lsum over key-pairs within wave (lane bits 3..5)
#pragma unroll
    for (int r = 0; r < TQ; ++r) {
        lsum[r] += __shfl_xor(lsum[r], 8);
        lsum[r] += __shfl_xor(lsum[r], 16);
        lsum[r] += __shfl_xor(lsum[r], 32);
    }
    if (lane < 8) {
#pragma unroll
        for (int r = 0; r < TQ; ++r)
            wl[wid * (TQ * HEADS) + r * 8 + lane] = lsum[r];
    }
    // stash O partials (two kk halves) in Pbuf-as-float
    {
        float* obuf = Pbuf;
#pragma unroll
        for (int hh = 0; hh < 4; ++hh) {
#pragma unroll
            for (int reg = 0; reg < 4; ++reg) {
                int m = frag_q * 4 + reg;
                obuf[kk * 2048 + (hbase + hh) * 256 + m * 16 + frag_m] = acc[hh][reg];
            }
        }
    }
    __syncthreads();
    if (t < 128) {
        const float* obuf = Pbuf;
#pragma unroll
        for (int r = 0; r < TQ; ++r) {
            int h = t >> 4, d = t & 15;
            float v = obuf[h * 256 + r * 16 + d] + obuf[2048 + h * 256 + r * 16 + d];
            Op[((size_t)sp * NSEQ + n0 + r) * HID + t] = v;
        }
        const int r2 = t >> 3, h2 = t & 7;
        float l = wl[r2 * 8 + h2] + wl[128 + r2 * 8 + h2] +
                  wl[256 + r2 * 8 + h2] + wl[384 + r2 * 8 + h2];
        Lp[((size_t)sp * NSEQ + n0 + r2) * HEADS + h2] = l;
    }
}

// ---------------- kernel D: combine splits + output projection ----------------
// grid 512 blocks x 128 threads, 4 rows per block
__global__ __launch_bounds__(128) void proj_kernel(
    const float* __restrict__ Op, const float* __restrict__ Lp,
    const float* __restrict__ WoT, const float* __restrict__ bo,
    float* __restrict__ out)
{
    __shared__ float xs[4 * HID];
    const int j = threadIdx.x;
    const int r0 = blockIdx.x * 4;
    const int hh = j >> 4;
#pragma unroll
    for (int r = 0; r < 4; ++r) {
        const size_t n = r0 + r;
        float s = 0.f, l = 0.f;
#pragma unroll
        for (int sp = 0; sp < SPLIT; ++sp) {
            s += Op[((size_t)sp * NSEQ + n) * HID + j];
            l += Lp[((size_t)sp * NSEQ + n) * HEADS + hh];
        }
        xs[r * HID + j] = s / l;
    }
    __syncthreads();
    float acc[4];
#pragma unroll
    for (int r = 0; r < 4; ++r) acc[r] = 0.f;
#pragma unroll 4
    for (int i = 0; i < HID; ++i) {
        float w = WoT[i * HID + j];
#pragma unroll
        for (int r = 0; r < 4; ++r) acc[r] = fmaf(xs[r * HID + i], w, acc[r]);
    }
    float b = bo[j];
#pragma unroll
    for (int r = 0; r < 4; ++r)
        out[(size_t)(r0 + r) * HID + j] = acc[r] + b;
}

extern "C" void kernel_launch(void* const* d_in, const int* in_sizes, int n_in,
                              void* d_out, int out_size, void* d_ws, size_t ws_size,
                              hipStream_t stream) {
    const float* x    = (const float*)d_in[0];
    const float* bias = (const float*)d_in[1];
    const unsigned char* mask = (const unsigned char*)d_in[2];
    const float* Wq = (const float*)d_in[3];
    const float* bq = (const float*)d_in[4];
    const float* Wk = (const float*)d_in[5];
    const float* bk = (const float*)d_in[6];
    const float* Wv = (const float*)d_in[7];
    const float* bv = (const float*)d_in[8];
    const float* Wo = (const float*)d_in[9];
    const float* bo = (const float*)d_in[10];
    float* out = (float*)d_out;

    float* w = (float*)d_ws;
    // ws layout (float offsets):
    float* WqT = w;                                     // 16384
    float* WkT = w + 16384;
    float* WvT = w + 32768;
    float* WoT = w + 49152;
    float* Qm  = w + 65536;                             // 262144 fp32
    __hip_bfloat16* Kb = (__hip_bfloat16*)(w + 327680); // 262144 bf16 rows [n][j]
    __hip_bfloat16* Vt = (__hip_bfloat16*)(w + 458752); // 262144 bf16 TRANSPOSED [j][n]
    float* Op  = w + 589824;                            // SPLIT*262144 fp32 (8 MB)
    float* Lp  = w + 589824 + (size_t)SPLIT * NSEQ * HID; // SPLIT*2048*8 fp32
    // total ~11.3 MB

    transpose_kernel<<<256, 256, 0, stream>>>(Wq, Wk, Wv, Wo, w);
    qkv_kernel<<<768, 128, 0, stream>>>(x, WqT, WkT, WvT, bq, bk, bv, Qm, Kb, Vt);
    attn_kernel<<<128 * SPLIT, 256, 0, stream>>>(Qm, Kb, Vt, bias, mask, Op, Lp);
    proj_kernel<<<512, 128, 0, stream>>>(Op, Lp, WoT, bo, out);
}